// Round 1
// baseline (10654.863 us; speedup 1.0000x reference)
//
#include <hip/hip_runtime.h>
#include <math.h>

#define TSTEPS 200
#define BATCH  256
#define XDIM   24
#define ADIM   8
#define INDIM  32
#define HID    512
#define OUTD   64

// ---------------------------------------------------------------------------
// zero the recurrent state (h double-buffer + c) — runs inside the graph so
// every replay starts from h0 = c0 = 0.
__global__ __launch_bounds__(256) void zero_ws_kernel(float* p, int n) {
    int i = blockIdx.x * 256 + threadIdx.x;
    if (i < n) p[i] = 0.0f;
}

// ---------------------------------------------------------------------------
// One LSTM timestep, fused: gates GEMM ([256,544]x[544,2048]) + pointwise.
// grid = (16 hidden-blocks, 16 batch-blocks), block = 256 threads.
// Block (hb, bb): batch rows bb*16..+15, hidden units hb*32..+31
//   -> 128 gate columns: {gate g in 0..3} x {unit u in 0..31}, row = g*512+hb*32+u
__global__ __launch_bounds__(256) void lstm_step_kernel(
    const float* __restrict__ x, const float* __restrict__ a,
    const float* __restrict__ mask,
    const float* __restrict__ W_ih, const float* __restrict__ W_hh,
    const float* __restrict__ b_ih, const float* __restrict__ b_hh,
    const float* __restrict__ h_in, float* __restrict__ h_out,
    float* __restrict__ c_state, int t)
{
    __shared__ float in_lds[16][544];     // 34816 B: [x*mask | a | h]
    __shared__ float w_lds[128][33];      // 16896 B: K-chunk of W, pad->bank (c+k)%32
    __shared__ float gate_lds[16][128];   //  8192 B
    __shared__ float bias_lds[128];

    const int tid = threadIdx.x;
    const int hb = blockIdx.x;
    const int bb = blockIdx.y;
    const int b0 = bb * 16;

    // ---- stage input rows: [16][544] = masked x (24) | a (8) | h_in (512)
    for (int idx = tid; idx < 16 * 544; idx += 256) {
        int i = idx / 544, k = idx - i * 544;
        int b = b0 + i;
        float v;
        if (k < XDIM) {
            v = x[(t * BATCH + b) * XDIM + k] * mask[(t * BATCH + b) * XDIM + k];
        } else if (k < INDIM) {
            v = a[(t * BATCH + b) * ADIM + (k - XDIM)];
        } else {
            v = h_in[b * HID + (k - INDIM)];
        }
        in_lds[i][k] = v;
    }
    if (tid < 128) {
        int g = tid >> 5, u = tid & 31;
        int row = g * HID + hb * 32 + u;
        bias_lds[tid] = b_ih[row] + b_hh[row];
    }
    __syncthreads();

    const int c_ = tid & 127;   // gate column 0..127
    const int bg = tid >> 7;    // batch half 0..1
    float acc[8];
#pragma unroll
    for (int j = 0; j < 8; ++j) acc[j] = bias_lds[c_];

    // ---- K loop: 17 chunks of 32 (chunk 0 = W_ih, chunks 1..16 = W_hh)
    for (int ch = 0; ch < 17; ++ch) {
        __syncthreads();
        {
            int r0 = tid >> 5, k = tid & 31;
            for (int r = r0; r < 128; r += 8) {
                int g = r >> 5, u = r & 31;
                int grow = g * HID + hb * 32 + u;
                w_lds[r][k] = (ch == 0)
                    ? W_ih[grow * INDIM + k]
                    : W_hh[grow * HID + (ch - 1) * 32 + k];
            }
        }
        __syncthreads();
        const int kg0 = ch * 32;
#pragma unroll
        for (int k = 0; k < 32; ++k) {
            float w = w_lds[c_][k];
#pragma unroll
            for (int j = 0; j < 8; ++j)
                acc[j] += w * in_lds[bg * 8 + j][kg0 + k];
        }
    }

    // ---- exchange gates, pointwise update
#pragma unroll
    for (int j = 0; j < 8; ++j) gate_lds[bg * 8 + j][c_] = acc[j];
    __syncthreads();

#pragma unroll
    for (int p = 0; p < 2; ++p) {
        int idx = tid * 2 + p;       // 0..511
        int i = idx >> 5;            // local batch 0..15
        int u = idx & 31;            // local unit  0..31
        float gi = gate_lds[i][u];
        float gf = gate_lds[i][32 + u];
        float gg = gate_lds[i][64 + u];
        float go = gate_lds[i][96 + u];
        float si = 1.0f / (1.0f + expf(-gi));
        float sf = 1.0f / (1.0f + expf(-gf));
        float so = 1.0f / (1.0f + expf(-go));
        float tg = tanhf(gg);
        int b = b0 + i;
        int hu = hb * 32 + u;
        float cold = c_state[b * HID + hu];
        float cnew = sf * cold + si * tg;
        c_state[b * HID + hu] = cnew;
        h_out[b * HID + hu] = so * tanhf(cnew);
    }
}

// ---------------------------------------------------------------------------
// Output heads: mu = exp(h@lin_w.T + lin_b)/10 ; log_var = h@lv_w.T + lv_b - 5
// grid = 256 (one block per batch row), block = 128 (wave0 -> mu, wave1 -> lv)
__global__ __launch_bounds__(128) void head_kernel(
    const float* __restrict__ h,
    const float* __restrict__ lin_w, const float* __restrict__ lin_b,
    const float* __restrict__ lv_w,  const float* __restrict__ lv_b,
    float* __restrict__ out)
{
    __shared__ float hl[HID];
    const int b = blockIdx.x, tid = threadIdx.x;
    for (int k = tid; k < HID; k += 128) hl[k] = h[b * HID + k];
    __syncthreads();

    const float* W = (tid < 64) ? lin_w : lv_w;
    const int j = tid & 63;
    float acc = 0.0f;
    for (int k = 0; k < HID; ++k) acc += W[j * HID + k] * hl[k];

    if (tid < 64) {
        out[b * OUTD + j] = expf(acc + lin_b[j]) * 0.1f;
    } else {
        out[BATCH * OUTD + b * OUTD + j] = acc + lv_b[j] - 5.0f;
    }
}

// ---------------------------------------------------------------------------
extern "C" void kernel_launch(void* const* d_in, const int* in_sizes, int n_in,
                              void* d_out, int out_size, void* d_ws, size_t ws_size,
                              hipStream_t stream)
{
    const float* x     = (const float*)d_in[0];
    const float* a     = (const float*)d_in[1];
    const float* mask  = (const float*)d_in[2];
    const float* W_ih  = (const float*)d_in[3];
    const float* W_hh  = (const float*)d_in[4];
    const float* b_ih  = (const float*)d_in[5];
    const float* b_hh  = (const float*)d_in[6];
    const float* lin_w = (const float*)d_in[7];
    const float* lin_b = (const float*)d_in[8];
    const float* lv_w  = (const float*)d_in[9];
    const float* lv_b  = (const float*)d_in[10];

    float* ws = (float*)d_ws;
    float* hbuf0 = ws;                       // [256*512]
    float* hbuf1 = ws + BATCH * HID;         // [256*512]
    float* cbuf  = ws + 2 * BATCH * HID;     // [256*512]
    const int state_n = 3 * BATCH * HID;

    zero_ws_kernel<<<(state_n + 255) / 256, 256, 0, stream>>>(ws, state_n);

    for (int s = 0; s < TSTEPS; ++s) {
        int t = TSTEPS - 1 - s;              // time-reversed scan
        const float* hin = (s & 1) ? hbuf1 : hbuf0;
        float* hout      = (s & 1) ? hbuf0 : hbuf1;
        lstm_step_kernel<<<dim3(16, 16), 256, 0, stream>>>(
            x, a, mask, W_ih, W_hh, b_ih, b_hh, hin, hout, cbuf, t);
    }

    const float* hfin = hbuf0;               // TSTEPS even -> last write was hbuf0
    head_kernel<<<BATCH, 128, 0, stream>>>(hfin, lin_w, lin_b, lv_w, lv_b,
                                           (float*)d_out);
}

// Round 2
// 2087.247 us; speedup vs baseline: 5.1047x; 5.1047x over previous
//
#include <hip/hip_runtime.h>
#include <math.h>
#include <stdint.h>

#define TSTEPS 200
#define BATCH  256
#define XDIM   24
#define ADIM   8
#define INDIM  32
#define HID    512
#define OUTD   64

#define NBT 8      // batch tiles (teams of blocks)
#define NUT 32     // unit-tile blocks per team
#define BT  32     // batch rows per block
#define UT  16     // hidden units per block
#define KTOT 544   // INDIM + HID
#define KK_N 17    // K chunks of 32

// ---- workspace byte layout ----
#define XA_OFF   0
#define XA_BYTES (TSTEPS*BATCH*INDIM*2)            // 3,276,800 (bf16 masked [x|a])
#define HB0_OFF  (XA_OFF + XA_BYTES)
#define HB_BYTES (BATCH*HID*2)                     // 262,144 (bf16 h)
#define HB1_OFF  (HB0_OFF + HB_BYTES)
#define HF_OFF   (HB1_OFF + HB_BYTES)              // final h, fp32
#define HF_BYTES (BATCH*HID*4)
#define FLAG_OFF (HF_OFF + HF_BYTES)
#define FLAG_N   (NBT*NUT)                          // 256 ints

// ---- LDS byte layout (single block) ----
#define ROWB 1104                     // in_lds row stride: 552 bf16 (544 + 8 pad)
#define IN_BYTES  (BT*ROWB)           // 35,328
#define W_OFF_L   IN_BYTES
#define W_BYTES   (4*KK_N*64*16)      // 69,632  (bf16 B-fragments, packed per-lane)
#define GATE_OFF_L (W_OFF_L + W_BYTES)        // 104,960
#define GATE_BYTES (4*BT*UT*4)                // 8,192 (fp32)
#define BIAS_OFF_L (GATE_OFF_L + GATE_BYTES)  // 113,152
#define LDS_TOTAL  (BIAS_OFF_L + 64*4)        // 113,408

typedef __attribute__((ext_vector_type(8))) short bf16x8;
typedef __attribute__((ext_vector_type(4))) float f32x4;

__device__ __forceinline__ unsigned short f2bf(float f) {
    union { float f; unsigned u; } c; c.f = f;
    unsigned u = c.u;
    unsigned r = (u + 0x7fffu + ((u >> 16) & 1u)) >> 16;
    return (unsigned short)r;
}

// ---------------------------------------------------------------------------
// precompute: xa[t][b][32] = bf16(concat(x*mask, a)); zero team flags
__global__ __launch_bounds__(256) void precompute_kernel(
    const float* __restrict__ x, const float* __restrict__ a,
    const float* __restrict__ mask, uint8_t* __restrict__ ws)
{
    unsigned short* xa = (unsigned short*)(ws + XA_OFF);
    int* flags = (int*)(ws + FLAG_OFF);
    const int n = TSTEPS * BATCH * INDIM;
    for (int e = blockIdx.x * 256 + threadIdx.x; e < n; e += gridDim.x * 256) {
        int t = e / (BATCH * INDIM);
        int r = e - t * (BATCH * INDIM);
        int b = r >> 5, j = r & 31;
        float v;
        if (j < XDIM) v = x[(t * BATCH + b) * XDIM + j] * mask[(t * BATCH + b) * XDIM + j];
        else          v = a[(t * BATCH + b) * ADIM + (j - XDIM)];
        xa[e] = f2bf(v);
    }
    int e0 = blockIdx.x * 256 + threadIdx.x;
    if (e0 < FLAG_N) flags[e0] = 0;
}

// ---------------------------------------------------------------------------
// persistent LSTM: 256 blocks = 8 batch-teams x 32 unit-blocks, 512 thr (8 waves)
// weights resident in LDS (bf16 MFMA fragment order) for all 200 steps.
__global__ __launch_bounds__(512, 1) void lstm_persist_kernel(
    const float* __restrict__ W_ih, const float* __restrict__ W_hh,
    const float* __restrict__ b_ih, const float* __restrict__ b_hh,
    uint8_t* __restrict__ ws)
{
    __shared__ __align__(16) uint8_t smem[LDS_TOTAL];
    const int tid = threadIdx.x;
    const int bid = blockIdx.x;
    const int bt = bid >> 5;           // team 0..7
    const int ut = bid & 31;           // unit tile 0..31
    const int b0 = bt * BT;
    const int ug0 = ut * UT;

    unsigned short* xa = (unsigned short*)(ws + XA_OFF);
    uint8_t* hbuf[2] = { ws + HB0_OFF, ws + HB1_OFF };
    float* hfinal = (float*)(ws + HF_OFF);
    int* flags = (int*)(ws + FLAG_OFF);

    // ---- prologue: pack weight slice into LDS as per-lane B fragments ----
    {
        unsigned short* wl = (unsigned short*)(smem + W_OFF_L);
        for (int idx = tid; idx < 64 * KTOT; idx += 512) {
            int r = idx / KTOT;            // 0..63 = g*16 + u
            int k = idx - r * KTOT;        // 0..543
            int g = r >> 4, u = r & 15;
            int grow = g * HID + ug0 + u;
            float v = (k < INDIM) ? W_ih[grow * INDIM + k]
                                  : W_hh[grow * HID + (k - INDIM)];
            int kk = k >> 5, kq = (k >> 3) & 3, j = k & 7;
            int lane = kq * 16 + u;
            wl[((g * KK_N + kk) * 64 + lane) * 8 + j] = f2bf(v);
        }
        float* bl = (float*)(smem + BIAS_OFF_L);
        if (tid < 64) {
            int g = tid >> 4, u = tid & 15;
            int grow = g * HID + ug0 + u;
            bl[tid] = b_ih[grow] + b_hh[grow];
        }
    }

    const int w = tid >> 6, l = tid & 63;
    const int mt = w >> 2;             // m-tile 0..1 (16 batch rows each)
    const int g  = w & 3;              // gate 0..3 (i,f,g,o)
    const int pb = tid >> 4, pu = tid & 15;  // pointwise (batch,unit) ownership
    float c_reg = 0.0f;

    for (int s = 0; s < TSTEPS; ++s) {
        const int t = TSTEPS - 1 - s;

        // ---- wait for whole team to finish step s-1 (wave 0 polls) ----
        if (s > 0) {
            if (tid < 64) {
                int fidx = bt * 32 + (l & 31);
                int iter = 0; bool done = false;
                do {
                    int f = (l < 32)
                        ? __hip_atomic_load(&flags[fidx], __ATOMIC_RELAXED,
                                            __HIP_MEMORY_SCOPE_AGENT)
                        : 0x7fffffff;
                    done = __all(f >= s);
                    if (!done) { __builtin_amdgcn_s_sleep(2); ++iter; }
                } while (!done && iter < (1 << 20));
                // acquire: invalidate stale L1/L2 before reading team h
                (void)__hip_atomic_load(&flags[bt * 32], __ATOMIC_ACQUIRE,
                                        __HIP_MEMORY_SCOPE_AGENT);
            }
        }
        __syncthreads();

        // ---- stage xa (64 B per row) ----
        {
            int b = tid >> 4, q = tid & 15;
            const unsigned int* src =
                (const unsigned int*)xa + ((size_t)(t * BATCH + b0 + b)) * 16 + q;
            *(unsigned int*)(smem + b * ROWB + q * 4) = *src;
        }
        // ---- stage h (zeros at s==0) ----
        if (s == 0) {
            bf16x8 zv = {0,0,0,0,0,0,0,0};
            for (int ch = tid; ch < BT * 64; ch += 512) {
                int b = ch >> 6, kc = ch & 63;
                *(bf16x8*)(smem + b * ROWB + 64 + kc * 16) = zv;
            }
        } else {
            const uint8_t* hr = hbuf[s & 1];
            for (int ch = tid; ch < BT * 64; ch += 512) {
                int b = ch >> 6, kc = ch & 63;
                bf16x8 v = *(const bf16x8*)(hr + (size_t)(b0 + b) * 1024 + kc * 16);
                *(bf16x8*)(smem + b * ROWB + 64 + kc * 16) = v;
            }
        }
        __syncthreads();

        // ---- MFMA: wave w -> (m-tile mt, gate g); K = 17 x 32 ----
        f32x4 acc = {0.f, 0.f, 0.f, 0.f};
        {
            const uint8_t* ab = smem + (mt * 16 + (l & 15)) * ROWB + (l >> 4) * 16;
            const uint8_t* bb = smem + W_OFF_L + ((g * KK_N) * 64 + l) * 16;
#pragma unroll
            for (int kk = 0; kk < KK_N; ++kk) {
                bf16x8 af = *(const bf16x8*)(ab + kk * 64);
                bf16x8 bf = *(const bf16x8*)(bb + kk * 1024);
                acc = __builtin_amdgcn_mfma_f32_16x16x32_bf16(af, bf, acc, 0, 0, 0);
            }
        }
        // D layout: col(=unit) = l&15, row(=batch) = (l>>4)*4 + r
        {
            float* gl = (float*)(smem + GATE_OFF_L);
            int u = l & 15;
            int brow = mt * 16 + (l >> 4) * 4;
#pragma unroll
            for (int r = 0; r < 4; ++r)
                gl[(g * BT + brow + r) * 16 + u] = acc[r];
        }
        __syncthreads();

        // ---- pointwise: thread owns (pb, pu); c in register ----
        {
            const float* gl = (const float*)(smem + GATE_OFF_L);
            const float* bl = (const float*)(smem + BIAS_OFF_L);
            float gi = gl[(0 * BT + pb) * 16 + pu] + bl[ 0 + pu];
            float gf = gl[(1 * BT + pb) * 16 + pu] + bl[16 + pu];
            float gg = gl[(2 * BT + pb) * 16 + pu] + bl[32 + pu];
            float go = gl[(3 * BT + pb) * 16 + pu] + bl[48 + pu];
            float i_ = 1.0f / (1.0f + __expf(-gi));
            float f_ = 1.0f / (1.0f + __expf(-gf));
            float o_ = 1.0f / (1.0f + __expf(-go));
            float g_ = 1.0f - 2.0f / (__expf(2.0f * gg) + 1.0f);
            c_reg = f_ * c_reg + i_ * g_;
            float h_ = o_ * (1.0f - 2.0f / (__expf(2.0f * c_reg) + 1.0f));
            *(unsigned short*)(hbuf[(s + 1) & 1] +
                ((size_t)(b0 + pb) * HID + ug0 + pu) * 2) = f2bf(h_);
            if (s == TSTEPS - 1)
                hfinal[(size_t)(b0 + pb) * HID + ug0 + pu] = h_;
        }
        __syncthreads();   // drains each wave's stores (vmcnt) before flag

        if (tid == 0 && s < TSTEPS - 1)
            __hip_atomic_store(&flags[bt * 32 + ut], s + 1, __ATOMIC_RELEASE,
                               __HIP_MEMORY_SCOPE_AGENT);
    }
}

// ---------------------------------------------------------------------------
// heads: mu = exp(h@lin_w.T + lin_b)/10 ; log_var = h@lv_w.T + lv_b - 5
__global__ __launch_bounds__(128) void head_kernel(
    const float* __restrict__ h,
    const float* __restrict__ lin_w, const float* __restrict__ lin_b,
    const float* __restrict__ lv_w,  const float* __restrict__ lv_b,
    float* __restrict__ out)
{
    __shared__ float hl[HID];
    const int b = blockIdx.x, tid = threadIdx.x;
    for (int k = tid; k < HID; k += 128) hl[k] = h[b * HID + k];
    __syncthreads();

    const float* W = (tid < 64) ? lin_w : lv_w;
    const int j = tid & 63;
    float acc = 0.0f;
    for (int k = 0; k < HID; ++k) acc += W[j * HID + k] * hl[k];

    if (tid < 64) {
        out[b * OUTD + j] = __expf(acc + lin_b[j]) * 0.1f;
    } else {
        out[BATCH * OUTD + b * OUTD + j] = acc + lv_b[j] - 5.0f;
    }
}

// ---------------------------------------------------------------------------
extern "C" void kernel_launch(void* const* d_in, const int* in_sizes, int n_in,
                              void* d_out, int out_size, void* d_ws, size_t ws_size,
                              hipStream_t stream)
{
    const float* x     = (const float*)d_in[0];
    const float* a     = (const float*)d_in[1];
    const float* mask  = (const float*)d_in[2];
    const float* W_ih  = (const float*)d_in[3];
    const float* W_hh  = (const float*)d_in[4];
    const float* b_ih  = (const float*)d_in[5];
    const float* b_hh  = (const float*)d_in[6];
    const float* lin_w = (const float*)d_in[7];
    const float* lin_b = (const float*)d_in[8];
    const float* lv_w  = (const float*)d_in[9];
    const float* lv_b  = (const float*)d_in[10];

    uint8_t* ws = (uint8_t*)d_ws;

    precompute_kernel<<<512, 256, 0, stream>>>(x, a, mask, ws);
    lstm_persist_kernel<<<NBT * NUT, 512, 0, stream>>>(W_ih, W_hh, b_ih, b_hh, ws);
    head_kernel<<<BATCH, 128, 0, stream>>>((const float*)(ws + HF_OFF),
                                           lin_w, lin_b, lv_w, lv_b, (float*)d_out);
}

// Round 3
// 1377.267 us; speedup vs baseline: 7.7362x; 1.5155x over previous
//
#include <hip/hip_runtime.h>
#include <math.h>
#include <stdint.h>

#define TSTEPS 200
#define BATCH  256
#define XDIM   24
#define ADIM   8
#define INDIM  32
#define HID    512
#define OUTD   64

#define NBT 8      // batch tiles (teams of blocks)
#define NUT 32     // unit-tile blocks per team
#define BT  32     // batch rows per block
#define UT  16     // hidden units per block
#define KTOT 544   // INDIM + HID
#define KK_N 17    // K chunks of 32

// ---- workspace byte layout ----
#define XA_OFF   0
#define XA_BYTES (TSTEPS*BATCH*INDIM*2)            // 3,276,800 (bf16 masked [x|a])
#define HB0_OFF  (XA_OFF + XA_BYTES)
#define HB_BYTES (BATCH*HID*2)                     // 262,144 (bf16 h)
#define HB1_OFF  (HB0_OFF + HB_BYTES)
#define HF_OFF   (HB1_OFF + HB_BYTES)              // final h, fp32
#define HF_BYTES (BATCH*HID*4)
#define FLAG_OFF (HF_OFF + HF_BYTES)
#define FLAG_N   (NBT*NUT)                          // 256 ints

// ---- LDS byte layout (single block) ----
#define ROWB 1104                     // in_lds row stride: 552 bf16 (544 + 8 pad)
#define IN_BYTES  (BT*ROWB)           // 35,328
#define W_OFF_L   IN_BYTES
#define W_BYTES   (4*KK_N*64*16)      // 69,632  (bf16 B-fragments, packed per-lane)
#define GATE_OFF_L (W_OFF_L + W_BYTES)        // 104,960
#define GATE_STRIDE 17                        // floats; breaks 4-way bank conflict
#define GATE_BYTES (4*BT*GATE_STRIDE*4)       // 8,704 (fp32)
#define BIAS_OFF_L (GATE_OFF_L + GATE_BYTES)  // 113,664
#define LDS_TOTAL  (BIAS_OFF_L + 64*4)        // 113,920

typedef __attribute__((ext_vector_type(8))) short bf16x8;
typedef __attribute__((ext_vector_type(4))) float f32x4;

__device__ __forceinline__ unsigned short f2bf(float f) {
    union { float f; unsigned u; } c; c.f = f;
    unsigned u = c.u;
    unsigned r = (u + 0x7fffu + ((u >> 16) & 1u)) >> 16;
    return (unsigned short)r;
}

// ---------------------------------------------------------------------------
// precompute: xa[t][b][32] = bf16(concat(x*mask, a)); zero flags + hbuf0
__global__ __launch_bounds__(256) void precompute_kernel(
    const float* __restrict__ x, const float* __restrict__ a,
    const float* __restrict__ mask, uint8_t* __restrict__ ws)
{
    unsigned short* xa = (unsigned short*)(ws + XA_OFF);
    int* flags = (int*)(ws + FLAG_OFF);
    unsigned* h0 = (unsigned*)(ws + HB0_OFF);
    const int n = TSTEPS * BATCH * INDIM;
    for (int e = blockIdx.x * 256 + threadIdx.x; e < n; e += gridDim.x * 256) {
        int t = e / (BATCH * INDIM);
        int r = e - t * (BATCH * INDIM);
        int b = r >> 5, j = r & 31;
        float v;
        if (j < XDIM) v = x[(t * BATCH + b) * XDIM + j] * mask[(t * BATCH + b) * XDIM + j];
        else          v = a[(t * BATCH + b) * ADIM + (j - XDIM)];
        xa[e] = f2bf(v);
    }
    int e0 = blockIdx.x * 256 + threadIdx.x;
    if (e0 < FLAG_N) flags[e0] = 0;
    if (e0 < HB_BYTES / 4) {
        for (int e = e0; e < HB_BYTES / 4; e += gridDim.x * 256) h0[e] = 0u;
    }
}

// ---------------------------------------------------------------------------
// persistent LSTM: 256 blocks = 8 batch-teams x 32 unit-blocks, 512 thr (8 waves)
// weights resident in LDS; h exchanged via LLC with sc1 (relaxed agent atomics),
// NO cache-invalidating acquire -> L2 stays warm for xa.
__global__ __launch_bounds__(512, 1) void lstm_persist_kernel(
    const float* __restrict__ W_ih, const float* __restrict__ W_hh,
    const float* __restrict__ b_ih, const float* __restrict__ b_hh,
    uint8_t* __restrict__ ws)
{
    __shared__ __align__(16) uint8_t smem[LDS_TOTAL];
    const int tid = threadIdx.x;
    const int bid = blockIdx.x;
    const int bt = bid >> 5;           // team 0..7
    const int ut = bid & 31;           // unit tile 0..31
    const int b0 = bt * BT;
    const int ug0 = ut * UT;

    unsigned short* xa = (unsigned short*)(ws + XA_OFF);
    uint8_t* hbuf[2] = { ws + HB0_OFF, ws + HB1_OFF };
    float* hfinal = (float*)(ws + HF_OFF);
    int* flags = (int*)(ws + FLAG_OFF);

    // ---- prologue: pack weight slice into LDS as per-lane B fragments ----
    {
        unsigned short* wl = (unsigned short*)(smem + W_OFF_L);
        for (int idx = tid; idx < 64 * KTOT; idx += 512) {
            int r = idx / KTOT;            // 0..63 = g*16 + u
            int k = idx - r * KTOT;        // 0..543
            int g = r >> 4, u = r & 15;
            int grow = g * HID + ug0 + u;
            float v = (k < INDIM) ? W_ih[grow * INDIM + k]
                                  : W_hh[grow * HID + (k - INDIM)];
            int kk = k >> 5, kq = (k >> 3) & 3, j = k & 7;
            int lane = kq * 16 + u;
            wl[((g * KK_N + kk) * 64 + lane) * 8 + j] = f2bf(v);
        }
        float* bl = (float*)(smem + BIAS_OFF_L);
        if (tid < 64) {
            int g = tid >> 4, u = tid & 15;
            int grow = g * HID + ug0 + u;
            bl[tid] = b_ih[grow] + b_hh[grow];
        }
    }

    const int w = tid >> 6, l = tid & 63;
    const int mt = w >> 2;             // m-tile 0..1 (16 batch rows each)
    const int g  = w & 3;              // gate 0..3 (i,f,g,o)
    const int pb = tid >> 4, pu = tid & 15;  // pointwise (batch,unit) ownership
    float c_reg = 0.0f;

    for (int s = 0; s < TSTEPS; ++s) {
        const int t = TSTEPS - 1 - s;

        // ---- wait for whole team to finish step s-1 (wave 0 polls, sc1) ----
        if (s > 0) {
            if (tid < 64) {
                int fidx = bt * 32 + (l & 31);
                int iter = 0; bool done = false;
                do {
                    int f = (l < 32)
                        ? __hip_atomic_load(&flags[fidx], __ATOMIC_RELAXED,
                                            __HIP_MEMORY_SCOPE_AGENT)
                        : 0x7fffffff;
                    done = __all(f >= s);
                    if (!done) { __builtin_amdgcn_s_sleep(2); ++iter; }
                } while (!done && iter < (1 << 20));
            }
        }
        __syncthreads();

        // ---- stage xa (64 B per row; normal loads, L2-resident) ----
        {
            int b = tid >> 4, q = tid & 15;
            const unsigned int* src =
                (const unsigned int*)xa + ((size_t)(t * BATCH + b0 + b)) * 16 + q;
            *(unsigned int*)(smem + b * ROWB + q * 4) = *src;
        }
        // ---- stage h from LLC (sc1 relaxed atomic u64 loads) ----
        {
            unsigned long long* hr = (unsigned long long*)hbuf[s & 1];
            for (int ch = tid; ch < BT * 128; ch += 512) {
                int b = ch >> 7, k8 = ch & 127;
                unsigned long long v = __hip_atomic_load(
                    hr + (((size_t)(b0 + b)) << 7) + k8,
                    __ATOMIC_RELAXED, __HIP_MEMORY_SCOPE_AGENT);
                *(unsigned long long*)(smem + b * ROWB + 64 + k8 * 8) = v;
            }
        }
        __syncthreads();

        // ---- MFMA: wave w -> (m-tile mt, gate g); K = 17 x 32 ----
        f32x4 acc = {0.f, 0.f, 0.f, 0.f};
        {
            const uint8_t* ab = smem + (mt * 16 + (l & 15)) * ROWB + (l >> 4) * 16;
            const uint8_t* bb = smem + W_OFF_L + ((g * KK_N) * 64 + l) * 16;
#pragma unroll
            for (int kk = 0; kk < KK_N; ++kk) {
                bf16x8 af = *(const bf16x8*)(ab + kk * 64);
                bf16x8 bf = *(const bf16x8*)(bb + kk * 1024);
                acc = __builtin_amdgcn_mfma_f32_16x16x32_bf16(af, bf, acc, 0, 0, 0);
            }
        }
        // D layout: col(=unit) = l&15, row(=batch) = (l>>4)*4 + r
        {
            float* gl = (float*)(smem + GATE_OFF_L);
            int u = l & 15;
            int brow = mt * 16 + (l >> 4) * 4;
#pragma unroll
            for (int r = 0; r < 4; ++r)
                gl[(g * BT + brow + r) * GATE_STRIDE + u] = acc[r];
        }
        __syncthreads();

        // ---- pointwise: thread owns (pb, pu); c in register ----
        {
            const float* gl = (const float*)(smem + GATE_OFF_L);
            const float* bl = (const float*)(smem + BIAS_OFF_L);
            float gi = gl[(0 * BT + pb) * GATE_STRIDE + pu] + bl[ 0 + pu];
            float gf = gl[(1 * BT + pb) * GATE_STRIDE + pu] + bl[16 + pu];
            float gg = gl[(2 * BT + pb) * GATE_STRIDE + pu] + bl[32 + pu];
            float go = gl[(3 * BT + pb) * GATE_STRIDE + pu] + bl[48 + pu];
            float i_ = 1.0f / (1.0f + __expf(-gi));
            float f_ = 1.0f / (1.0f + __expf(-gf));
            float o_ = 1.0f / (1.0f + __expf(-go));
            float g_ = 1.0f - 2.0f / (__expf(2.0f * gg) + 1.0f);
            c_reg = f_ * c_reg + i_ * g_;
            float h_ = o_ * (1.0f - 2.0f / (__expf(2.0f * c_reg) + 1.0f));

            // pack 2 bf16 -> u32, write-through to LLC (sc1 relaxed atomic)
            unsigned hv = (unsigned)f2bf(h_);
            unsigned ov = (unsigned)__shfl_xor((int)hv, 1);
            if ((tid & 1) == 0) {
                unsigned packed = hv | (ov << 16);
                unsigned idx = (((unsigned)(b0 + pb)) * HID + ug0 + pu) >> 1;
                __hip_atomic_store((unsigned*)hbuf[(s + 1) & 1] + idx, packed,
                                   __ATOMIC_RELAXED, __HIP_MEMORY_SCOPE_AGENT);
            }
            if (s == TSTEPS - 1)
                hfinal[(size_t)(b0 + pb) * HID + ug0 + pu] = h_;
        }
        __syncthreads();   // each wave drains vmcnt before barrier -> stores done

        if (tid == 0 && s < TSTEPS - 1)
            __hip_atomic_store(&flags[bt * 32 + ut], s + 1, __ATOMIC_RELEASE,
                               __HIP_MEMORY_SCOPE_AGENT);
    }
}

// ---------------------------------------------------------------------------
// heads: mu = exp(h@lin_w.T + lin_b)/10 ; log_var = h@lv_w.T + lv_b - 5
__global__ __launch_bounds__(128) void head_kernel(
    const float* __restrict__ h,
    const float* __restrict__ lin_w, const float* __restrict__ lin_b,
    const float* __restrict__ lv_w,  const float* __restrict__ lv_b,
    float* __restrict__ out)
{
    __shared__ float hl[HID];
    const int b = blockIdx.x, tid = threadIdx.x;
    for (int k = tid; k < HID; k += 128) hl[k] = h[b * HID + k];
    __syncthreads();

    const float* W = (tid < 64) ? lin_w : lv_w;
    const int j = tid & 63;
    float acc = 0.0f;
    for (int k = 0; k < HID; ++k) acc += W[j * HID + k] * hl[k];

    if (tid < 64) {
        out[b * OUTD + j] = __expf(acc + lin_b[j]) * 0.1f;
    } else {
        out[BATCH * OUTD + b * OUTD + j] = acc + lv_b[j] - 5.0f;
    }
}

// ---------------------------------------------------------------------------
extern "C" void kernel_launch(void* const* d_in, const int* in_sizes, int n_in,
                              void* d_out, int out_size, void* d_ws, size_t ws_size,
                              hipStream_t stream)
{
    const float* x     = (const float*)d_in[0];
    const float* a     = (const float*)d_in[1];
    const float* mask  = (const float*)d_in[2];
    const float* W_ih  = (const float*)d_in[3];
    const float* W_hh  = (const float*)d_in[4];
    const float* b_ih  = (const float*)d_in[5];
    const float* b_hh  = (const float*)d_in[6];
    const float* lin_w = (const float*)d_in[7];
    const float* lin_b = (const float*)d_in[8];
    const float* lv_w  = (const float*)d_in[9];
    const float* lv_b  = (const float*)d_in[10];

    uint8_t* ws = (uint8_t*)d_ws;

    precompute_kernel<<<512, 256, 0, stream>>>(x, a, mask, ws);
    lstm_persist_kernel<<<NBT * NUT, 512, 0, stream>>>(W_ih, W_hh, b_ih, b_hh, ws);
    head_kernel<<<BATCH, 128, 0, stream>>>((const float*)(ws + HF_OFF),
                                           lin_w, lin_b, lv_w, lv_b, (float*)d_out);
}

// Round 4
// 1130.302 us; speedup vs baseline: 9.4266x; 1.2185x over previous
//
#include <hip/hip_runtime.h>
#include <math.h>
#include <stdint.h>

#define TSTEPS 200
#define BATCH  256
#define XDIM   24
#define ADIM   8
#define INDIM  32
#define HID    512
#define OUTD   64

#define NBT 8      // batch teams
#define NUT 32     // unit-tile blocks per team
#define BT  32     // batch rows per block
#define UT  16     // hidden units per block
#define KTOT 544   // INDIM + HID
#define KK_N 17    // K chunks of 32

// ---- workspace byte layout ----
#define XA_OFF   0
#define XA_BYTES (TSTEPS*BATCH*INDIM*2)              // 3,276,800 bf16 [x*mask|a]
#define HB_BYTES (BATCH*HID*2)                       // 262,144 bf16 h
#define HB_OFF(i) (XA_OFF + XA_BYTES + (size_t)(i)*HB_BYTES)   // ring of 3
#define HF_OFF   (XA_OFF + XA_BYTES + 3*(size_t)HB_BYTES)      // final h fp32
#define HF_BYTES (BATCH*HID*4)

// ---- LDS byte layout ----
#define ROWB 1104                     // 552 bf16 per row (544 + 8 pad)
#define IN_BYTES  (BT*ROWB)           // 35,328
#define W_OFF_L   IN_BYTES
#define W_BYTES   (4*KK_N*64*16)      // 69,632 bf16 B-fragments
#define GATE_OFF_L (W_OFF_L + W_BYTES)
#define GATE_STRIDE 17
#define GATE_BYTES (4*BT*GATE_STRIDE*4)       // 8,704
#define BIAS_OFF_L (GATE_OFF_L + GATE_BYTES)
#define LDS_TOTAL  (BIAS_OFF_L + 64*4)        // 113,920

typedef __attribute__((ext_vector_type(8))) short bf16x8;
typedef __attribute__((ext_vector_type(4))) float f32x4;

__device__ __forceinline__ unsigned short f2bf(float f) {
    union { float f; unsigned u; } c; c.f = f;
    unsigned u = c.u;
    return (unsigned short)((u + 0x7fffu + ((u >> 16) & 1u)) >> 16);
}
__device__ __forceinline__ unsigned long long llc_load64(const unsigned long long* p) {
    return __hip_atomic_load(p, __ATOMIC_RELAXED, __HIP_MEMORY_SCOPE_AGENT);
}
__device__ __forceinline__ void llc_store32(unsigned* p, unsigned v) {
    __hip_atomic_store(p, v, __ATOMIC_RELAXED, __HIP_MEMORY_SCOPE_AGENT);
}
__device__ __forceinline__ void llc_store64(unsigned long long* p, unsigned long long v) {
    __hip_atomic_store(p, v, __ATOMIC_RELAXED, __HIP_MEMORY_SCOPE_AGENT);
}

// ---------------------------------------------------------------------------
// precompute: xa bf16; hbuf0 = 0, hbuf1/2 = sentinel 0xFFFFFFFF
__global__ __launch_bounds__(256) void precompute_kernel(
    const float* __restrict__ x, const float* __restrict__ a,
    const float* __restrict__ mask, uint8_t* __restrict__ ws)
{
    unsigned short* xa = (unsigned short*)(ws + XA_OFF);
    const int n = TSTEPS * BATCH * INDIM;
    for (int e = blockIdx.x * 256 + threadIdx.x; e < n; e += gridDim.x * 256) {
        int t = e / (BATCH * INDIM);
        int r = e - t * (BATCH * INDIM);
        int b = r >> 5, j = r & 31;
        float v;
        if (j < XDIM) v = x[(t * BATCH + b) * XDIM + j] * mask[(t * BATCH + b) * XDIM + j];
        else          v = a[(t * BATCH + b) * ADIM + (j - XDIM)];
        xa[e] = f2bf(v);
    }
    unsigned* h0 = (unsigned*)(ws + HB_OFF(0));
    unsigned* h1 = (unsigned*)(ws + HB_OFF(1));
    unsigned* h2 = (unsigned*)(ws + HB_OFF(2));
    const int hn = HB_BYTES / 4;
    for (int e = blockIdx.x * 256 + threadIdx.x; e < hn; e += gridDim.x * 256) {
        h0[e] = 0u; h1[e] = 0xFFFFFFFFu; h2[e] = 0xFFFFFFFFu;
    }
}

// ---------------------------------------------------------------------------
// persistent LSTM: 256 blocks = 8 teams x 32 unit-blocks, 512 thr (8 waves).
// Sync = data-sentinel polling on a 3-ring of LLC h buffers; 2 barriers/step.
__global__ __launch_bounds__(512, 1) void lstm_persist_kernel(
    const float* __restrict__ W_ih, const float* __restrict__ W_hh,
    const float* __restrict__ b_ih, const float* __restrict__ b_hh,
    uint8_t* __restrict__ ws)
{
    __shared__ __align__(16) uint8_t smem[LDS_TOTAL];
    const int tid = threadIdx.x;
    const int bid = blockIdx.x;
    const int bt = bid >> 5;
    const int ut = bid & 31;
    const int b0 = bt * BT;
    const int ug0 = ut * UT;

    const unsigned* xa32 = (const unsigned*)(ws + XA_OFF);
    unsigned long long* hb[3] = {
        (unsigned long long*)(ws + HB_OFF(0)),
        (unsigned long long*)(ws + HB_OFF(1)),
        (unsigned long long*)(ws + HB_OFF(2)) };
    float* hfinal = (float*)(ws + HF_OFF);

    // ---- prologue: pack weight slice into LDS as per-lane B fragments ----
    {
        unsigned short* wl = (unsigned short*)(smem + W_OFF_L);
        for (int idx = tid; idx < 64 * KTOT; idx += 512) {
            int r = idx / KTOT;
            int k = idx - r * KTOT;
            int g = r >> 4, u = r & 15;
            int grow = g * HID + ug0 + u;
            float v = (k < INDIM) ? W_ih[grow * INDIM + k]
                                  : W_hh[grow * HID + (k - INDIM)];
            int kk = k >> 5, kq = (k >> 3) & 3, j = k & 7;
            int lane = kq * 16 + u;
            wl[((g * KK_N + kk) * 64 + lane) * 8 + j] = f2bf(v);
        }
        float* bl = (float*)(smem + BIAS_OFF_L);
        if (tid < 64) {
            int g = tid >> 4, u = tid & 15;
            int grow = g * HID + ug0 + u;
            bl[tid] = b_ih[grow] + b_hh[grow];
        }
    }

    const int w = tid >> 6, l = tid & 63;
    const int mt = w >> 2;             // m-tile 0..1
    const int g  = w & 3;              // gate 0..3
    const int prow = tid >> 4;         // batch row 0..31 (xa/poll/pointwise)
    const int pcol = tid & 15;
    float c_reg = 0.0f;

    // prefetch xa for s=0 (t = TSTEPS-1)
    unsigned xa_next = xa32[((size_t)(TSTEPS - 1) * BATCH + b0 + prow) * 16 + pcol];

    const float* gl = (const float*)(smem + GATE_OFF_L);
    const float* bl = (const float*)(smem + BIAS_OFF_L);

    for (int s = 0; s < TSTEPS; ++s) {
        // ================= phase P =================
        // xa -> LDS
        *(unsigned*)(smem + prow * ROWB + pcol * 4) = xa_next;

        // pointwise for step s-1: produce h(s), write-through to ring buf s%3
        if (s > 0) {
            float gi = gl[(0 * BT + prow) * GATE_STRIDE + pcol];
            float gf = gl[(1 * BT + prow) * GATE_STRIDE + pcol];
            float gg = gl[(2 * BT + prow) * GATE_STRIDE + pcol];
            float go = gl[(3 * BT + prow) * GATE_STRIDE + pcol];
            float i_ = 1.0f / (1.0f + __expf(-gi));
            float f_ = 1.0f / (1.0f + __expf(-gf));
            float o_ = 1.0f / (1.0f + __expf(-go));
            float g_ = 1.0f - 2.0f / (__expf(2.0f * gg) + 1.0f);
            c_reg = f_ * c_reg + i_ * g_;
            float h_ = o_ * (1.0f - 2.0f / (__expf(2.0f * c_reg) + 1.0f));
            unsigned hv = (unsigned)f2bf(h_);
            unsigned ov = (unsigned)__shfl_xor((int)hv, 1);
            if (!(tid & 1)) {
                unsigned packed = hv | (ov << 16);
                unsigned idx = (((unsigned)(b0 + prow)) * HID + ug0 + pcol) >> 1;
                llc_store32((unsigned*)hb[s % 3] + idx, packed);
            }
        }

        // poll + stage h(s): thread owns 8 u64 slots of row (b0+prow)
        {
            const unsigned long long* hr = hb[s % 3] + (((size_t)(b0 + prow)) << 7);
            unsigned long long vals[8];
            unsigned vm = 0;
#pragma unroll
            for (int j = 0; j < 8; ++j) vals[j] = llc_load64(hr + pcol + 16 * j);
            int rounds = 0;
            while (true) {
#pragma unroll
                for (int j = 0; j < 8; ++j) {
                    if (!(vm & (1u << j))) {
                        unsigned lo = (unsigned)vals[j];
                        unsigned hi = (unsigned)(vals[j] >> 32);
                        if (lo != 0xFFFFFFFFu && hi != 0xFFFFFFFFu) vm |= 1u << j;
                    }
                }
                if (vm == 0xFFu || rounds > (1 << 20)) break;
                __builtin_amdgcn_s_sleep(1);
                ++rounds;
#pragma unroll
                for (int j = 0; j < 8; ++j)
                    if (!(vm & (1u << j))) vals[j] = llc_load64(hr + pcol + 16 * j);
            }
#pragma unroll
            for (int j = 0; j < 8; ++j)
                *(unsigned long long*)(smem + prow * ROWB + 64 + (pcol + 16 * j) * 8) = vals[j];
        }

        // sentinel-reset own slice of ring buf (s+2)%3 (safe post-poll)
        if (s >= 1 && tid < 128) {
            unsigned long long* rb = hb[(s + 2) % 3]
                + (((size_t)(b0 + (tid >> 2))) << 7) + (ug0 >> 2) + (tid & 3);
            llc_store64(rb, ~0ULL);
        }
        __syncthreads();

        // ================= compute phase =================
        float binit = bl[g * 16 + (l & 15)];
        f32x4 acc = { binit, binit, binit, binit };
        {
            const uint8_t* ab = smem + (mt * 16 + (l & 15)) * ROWB + (l >> 4) * 16;
            const uint8_t* bb = smem + W_OFF_L + ((g * KK_N) * 64 + l) * 16;
#pragma unroll
            for (int kk = 0; kk < KK_N; ++kk) {
                bf16x8 af = *(const bf16x8*)(ab + kk * 64);
                bf16x8 bf = *(const bf16x8*)(bb + kk * 1024);
                acc = __builtin_amdgcn_mfma_f32_16x16x32_bf16(af, bf, acc, 0, 0, 0);
            }
        }
        {
            float* glw = (float*)(smem + GATE_OFF_L);
            int u = l & 15;
            int brow = mt * 16 + (l >> 4) * 4;
#pragma unroll
            for (int r = 0; r < 4; ++r)
                glw[(g * BT + brow + r) * GATE_STRIDE + u] = acc[r];
        }
        // prefetch xa for next step
        if (s < TSTEPS - 1)
            xa_next = xa32[((size_t)(TSTEPS - 2 - s) * BATCH + b0 + prow) * 16 + pcol];
        __syncthreads();
    }

    // ---- final pointwise (step TSTEPS-1) -> hfinal fp32 ----
    {
        float gi = gl[(0 * BT + prow) * GATE_STRIDE + pcol];
        float gf = gl[(1 * BT + prow) * GATE_STRIDE + pcol];
        float gg = gl[(2 * BT + prow) * GATE_STRIDE + pcol];
        float go = gl[(3 * BT + prow) * GATE_STRIDE + pcol];
        float i_ = 1.0f / (1.0f + __expf(-gi));
        float f_ = 1.0f / (1.0f + __expf(-gf));
        float o_ = 1.0f / (1.0f + __expf(-go));
        float g_ = 1.0f - 2.0f / (__expf(2.0f * gg) + 1.0f);
        c_reg = f_ * c_reg + i_ * g_;
        float h_ = o_ * (1.0f - 2.0f / (__expf(2.0f * c_reg) + 1.0f));
        hfinal[(size_t)(b0 + prow) * HID + ug0 + pcol] = h_;
    }
}

// ---------------------------------------------------------------------------
// heads: mu = exp(h@lin_w.T + lin_b)/10 ; log_var = h@lv_w.T + lv_b - 5
__global__ __launch_bounds__(128) void head_kernel(
    const float* __restrict__ h,
    const float* __restrict__ lin_w, const float* __restrict__ lin_b,
    const float* __restrict__ lv_w,  const float* __restrict__ lv_b,
    float* __restrict__ out)
{
    __shared__ float hl[HID];
    const int b = blockIdx.x, tid = threadIdx.x;
    for (int k = tid; k < HID; k += 128) hl[k] = h[b * HID + k];
    __syncthreads();

    const float* W = (tid < 64) ? lin_w : lv_w;
    const int j = tid & 63;
    const float4* W4 = (const float4*)(W + j * HID);
    float acc = 0.0f;
    for (int k4 = 0; k4 < HID / 4; ++k4) {
        float4 wv = W4[k4];
        float4 hv = *(const float4*)(hl + k4 * 4);
        acc += wv.x * hv.x + wv.y * hv.y + wv.z * hv.z + wv.w * hv.w;
    }

    if (tid < 64) {
        out[b * OUTD + j] = __expf(acc + lin_b[j]) * 0.1f;
    } else {
        out[BATCH * OUTD + b * OUTD + j] = acc + lv_b[j] - 5.0f;
    }
}

// ---------------------------------------------------------------------------
extern "C" void kernel_launch(void* const* d_in, const int* in_sizes, int n_in,
                              void* d_out, int out_size, void* d_ws, size_t ws_size,
                              hipStream_t stream)
{
    const float* x     = (const float*)d_in[0];
    const float* a     = (const float*)d_in[1];
    const float* mask  = (const float*)d_in[2];
    const float* W_ih  = (const float*)d_in[3];
    const float* W_hh  = (const float*)d_in[4];
    const float* b_ih  = (const float*)d_in[5];
    const float* b_hh  = (const float*)d_in[6];
    const float* lin_w = (const float*)d_in[7];
    const float* lin_b = (const float*)d_in[8];
    const float* lv_w  = (const float*)d_in[9];
    const float* lv_b  = (const float*)d_in[10];

    uint8_t* ws = (uint8_t*)d_ws;

    precompute_kernel<<<512, 256, 0, stream>>>(x, a, mask, ws);
    lstm_persist_kernel<<<NBT * NUT, 512, 0, stream>>>(W_ih, W_hh, b_ih, b_hh, ws);
    head_kernel<<<BATCH, 128, 0, stream>>>((const float*)(ws + HF_OFF),
                                           lin_w, lin_b, lv_w, lv_b, (float*)d_out);
}

// Round 5
// 842.011 us; speedup vs baseline: 12.6541x; 1.3424x over previous
//
#include <hip/hip_runtime.h>
#include <math.h>
#include <stdint.h>

#define TSTEPS 200
#define BATCH  256
#define XDIM   24
#define ADIM   8
#define INDIM  32
#define HID    512
#define OUTD   64

#define NBT 8      // batch teams
#define NUT 32     // unit-tile blocks per team
#define BT  32     // batch rows per block
#define UT  16     // hidden units per block
#define KTOT 544
#define KK_N 17    // K chunks of 32

// ---- workspace byte layout ----
#define XA_OFF   0
#define XA_BYTES (TSTEPS*BATCH*INDIM*2)              // 3,276,800 bf16 [x*mask|a]
#define HB_BYTES (BATCH*HID*2)                       // 262,144 bf16 h
#define HB_OFF(i) (XA_OFF + XA_BYTES + (size_t)(i)*HB_BYTES)   // ring of 3
#define HF_OFF   (XA_OFF + XA_BYTES + 3*(size_t)HB_BYTES)      // final h fp32

// ---- LDS byte layout ----
#define ROWB 1104                     // 64 B xa + 1024 B h + 16 B pad
#define IN_BYTES  (BT*ROWB)           // 35,328 ; double-buffered
#define SCR_OFF   (2*IN_BYTES)        // 70,656 ; per-wave 1 KB scratch
#define SCR_BYTES (8*1024)
#define LDS_TOTAL (SCR_OFF + SCR_BYTES)  // 78,848

typedef __attribute__((ext_vector_type(8))) short bf16x8;
typedef __attribute__((ext_vector_type(4))) float f32x4;

__device__ __forceinline__ unsigned short f2bf(float f) {
    union { float f; unsigned u; } c; c.f = f;
    unsigned u = c.u;
    return (unsigned short)((u + 0x7fffu + ((u >> 16) & 1u)) >> 16);
}
__device__ __forceinline__ bf16x8 pack8(const float* p) {
    float4 lo = *(const float4*)p, hi = *(const float4*)(p + 4);
    union { unsigned short s[8]; bf16x8 v; } u;
    u.s[0] = f2bf(lo.x); u.s[1] = f2bf(lo.y); u.s[2] = f2bf(lo.z); u.s[3] = f2bf(lo.w);
    u.s[4] = f2bf(hi.x); u.s[5] = f2bf(hi.y); u.s[6] = f2bf(hi.z); u.s[7] = f2bf(hi.w);
    return u.v;
}
__device__ __forceinline__ unsigned long long llc_load64(const unsigned long long* p) {
    return __hip_atomic_load(p, __ATOMIC_RELAXED, __HIP_MEMORY_SCOPE_AGENT);
}
__device__ __forceinline__ void llc_store64(unsigned long long* p, unsigned long long v) {
    __hip_atomic_store(p, v, __ATOMIC_RELAXED, __HIP_MEMORY_SCOPE_AGENT);
}

// ---------------------------------------------------------------------------
// precompute: xa bf16; hbuf0 = 0 (h at s=0), hbuf1/2 = sentinel
__global__ __launch_bounds__(256) void precompute_kernel(
    const float* __restrict__ x, const float* __restrict__ a,
    const float* __restrict__ mask, uint8_t* __restrict__ ws)
{
    unsigned short* xa = (unsigned short*)(ws + XA_OFF);
    const int n = TSTEPS * BATCH * INDIM;
    for (int e = blockIdx.x * 256 + threadIdx.x; e < n; e += gridDim.x * 256) {
        int t = e / (BATCH * INDIM);
        int r = e - t * (BATCH * INDIM);
        int b = r >> 5, j = r & 31;
        float v;
        if (j < XDIM) v = x[(t * BATCH + b) * XDIM + j] * mask[(t * BATCH + b) * XDIM + j];
        else          v = a[(t * BATCH + b) * ADIM + (j - XDIM)];
        xa[e] = f2bf(v);
    }
    unsigned* h0 = (unsigned*)(ws + HB_OFF(0));
    unsigned* h1 = (unsigned*)(ws + HB_OFF(1));
    unsigned* h2 = (unsigned*)(ws + HB_OFF(2));
    const int hn = HB_BYTES / 4;
    for (int e = blockIdx.x * 256 + threadIdx.x; e < hn; e += gridDim.x * 256) {
        h0[e] = 0u; h1[e] = 0xFFFFFFFFu; h2[e] = 0xFFFFFFFFu;
    }
}

// ---------------------------------------------------------------------------
// persistent LSTM: 256 blocks = 8 teams x 32 unit-blocks, 512 thr (8 waves).
// Weights live in VGPRs (B fragments, gate-interleaved cols); gates transposed
// in-wave via 1 KB LDS scratch; ONE barrier per step; data-sentinel 3-ring.
__global__ __launch_bounds__(512, 1) void lstm_persist_kernel(
    const float* __restrict__ W_ih, const float* __restrict__ W_hh,
    const float* __restrict__ b_ih, const float* __restrict__ b_hh,
    uint8_t* __restrict__ ws)
{
    __shared__ __align__(16) uint8_t smem[LDS_TOTAL];
    const int tid = threadIdx.x;
    const int bid = blockIdx.x;
    const int bt = bid >> 5;
    const int ut = bid & 31;
    const int b0 = bt * BT;
    const int ug0 = ut * UT;

    const unsigned* xa32 = (const unsigned*)(ws + XA_OFF);
    unsigned long long* hb[3] = {
        (unsigned long long*)(ws + HB_OFF(0)),
        (unsigned long long*)(ws + HB_OFF(1)),
        (unsigned long long*)(ws + HB_OFF(2)) };
    float* hfinal = (float*)(ws + HF_OFF);

    const int w  = tid >> 6, l = tid & 63;
    const int mt = w >> 2;             // m-tile (16 batch rows)
    const int ct = w & 3;              // col-tile: units ct*4..ct*4+3, all 4 gates
    const int c  = l & 15;             // MFMA col: gate gp = c>>2, unit-sub du_b = c&3
    const int kq = l >> 4;             // k-quad
    const int grow = (c >> 2) * HID + ug0 + ct * 4 + (c & 3);

    // ---- B fragments -> registers (constant all 200 steps) ----
    bf16x8 wb[KK_N];
    wb[0] = pack8(W_ih + (size_t)grow * INDIM + kq * 8);
#pragma unroll
    for (int kk = 1; kk < KK_N; ++kk)
        wb[kk] = pack8(W_hh + (size_t)grow * HID + (kk - 1) * 32 + kq * 8);
    const float bias = b_ih[grow] + b_hh[grow];

    // pointwise ownership: lane -> (unit-sub du, row-sub rs) of this wave's tile
    const int du = l & 3, rs = l >> 2;
    // staging ownership: thread -> (row prow, chunk pcol)
    const int prow = tid >> 4, pcol = tid & 15;
    float c_reg = 0.0f;

    float* scr = (float*)(smem + SCR_OFF + w * 1024);

    unsigned xa_next = xa32[((size_t)(TSTEPS - 1) * BATCH + b0 + prow) * 16 + pcol];

    for (int s = 0; s < TSTEPS; ++s) {
        uint8_t* inb = smem + (s & 1) * IN_BYTES;

        // xa -> LDS
        *(unsigned*)(inb + prow * ROWB + pcol * 4) = xa_next;

        // poll + stage h(s) (8 u64 per thread)
        {
            const unsigned long long* hr = hb[s % 3] + (((size_t)(b0 + prow)) << 7);
            unsigned long long vals[8];
            unsigned vm = 0;
#pragma unroll
            for (int j = 0; j < 8; ++j) vals[j] = llc_load64(hr + pcol + 16 * j);
            int rounds = 0;
            while (true) {
#pragma unroll
                for (int j = 0; j < 8; ++j) {
                    if (!(vm & (1u << j))) {
                        unsigned lo = (unsigned)vals[j];
                        unsigned hi = (unsigned)(vals[j] >> 32);
                        if (lo != 0xFFFFFFFFu && hi != 0xFFFFFFFFu) vm |= 1u << j;
                    }
                }
                if (vm == 0xFFu || rounds > (1 << 20)) break;
                __builtin_amdgcn_s_sleep(1);
                ++rounds;
#pragma unroll
                for (int j = 0; j < 8; ++j)
                    if (!(vm & (1u << j))) vals[j] = llc_load64(hr + pcol + 16 * j);
            }
#pragma unroll
            for (int j = 0; j < 8; ++j)
                *(unsigned long long*)(inb + prow * ROWB + 64 + (pcol + 16 * j) * 8) = vals[j];
        }

        // sentinel-reset own slice of ring buf (s+2)%3 (read at s-1; safe post-poll)
        if (s >= 1 && tid < 128) {
            unsigned long long* rb = hb[(s + 2) % 3]
                + (((size_t)(b0 + (tid >> 2))) << 7) + ut * 4 + (tid & 3);
            llc_store64(rb, ~0ULL);
        }
        // prefetch next xa
        if (s < TSTEPS - 1)
            xa_next = xa32[((size_t)(TSTEPS - 2 - s) * BATCH + b0 + prow) * 16 + pcol];

        __syncthreads();

        // ---- MFMA: A from LDS, B from regs; bias folded into acc init ----
        f32x4 acc = { bias, bias, bias, bias };
        const uint8_t* ab = inb + (mt * 16 + c) * ROWB + kq * 16;
#pragma unroll
        for (int kk = 0; kk < KK_N; ++kk) {
            bf16x8 af = *(const bf16x8*)(ab + kk * 64);
            acc = __builtin_amdgcn_mfma_f32_16x16x32_bf16(af, wb[kk], acc, 0, 0, 0);
        }

        // ---- in-wave gate transpose via per-wave scratch (no barrier) ----
        *(f32x4*)(scr + l * 4) = acc;
        // lane (du, rs): gate j at scr[((rs>>2)*16 + j*4 + du)*4 + (rs&3)]
        float gi = scr[(((rs >> 2) * 16 +  0 + du) << 2) + (rs & 3)];
        float gf = scr[(((rs >> 2) * 16 +  4 + du) << 2) + (rs & 3)];
        float gg = scr[(((rs >> 2) * 16 +  8 + du) << 2) + (rs & 3)];
        float go = scr[(((rs >> 2) * 16 + 12 + du) << 2) + (rs & 3)];

        float i_ = 1.0f / (1.0f + __expf(-gi));
        float f_ = 1.0f / (1.0f + __expf(-gf));
        float o_ = 1.0f / (1.0f + __expf(-go));
        float g_ = 1.0f - 2.0f / (__expf(2.0f * gg) + 1.0f);
        c_reg = f_ * c_reg + i_ * g_;
        float h_ = o_ * (1.0f - 2.0f / (__expf(2.0f * c_reg) + 1.0f));

        const int grow_b = b0 + mt * 16 + rs;          // global batch row
        if (s < TSTEPS - 1) {
            // pack 4 units (this wave's span) -> u64, store by du==0 lanes
            unsigned v = (unsigned)f2bf(h_);
            unsigned t1 = (unsigned)__shfl_xor((int)v, 1);
            unsigned packed = v | (t1 << 16);
            unsigned hi = (unsigned)__shfl_xor((int)packed, 2);
            if (du == 0) {
                unsigned long long u64v = (unsigned long long)packed |
                                          ((unsigned long long)hi << 32);
                llc_store64(hb[(s + 1) % 3] + (size_t)grow_b * 128 + ut * 4 + ct, u64v);
            }
        } else {
            hfinal[(size_t)grow_b * HID + ug0 + ct * 4 + du] = h_;
        }
    }
}

// ---------------------------------------------------------------------------
// heads: mu = exp(h@lin_w.T + lin_b)/10 ; log_var = h@lv_w.T + lv_b - 5
__global__ __launch_bounds__(128) void head_kernel(
    const float* __restrict__ h,
    const float* __restrict__ lin_w, const float* __restrict__ lin_b,
    const float* __restrict__ lv_w,  const float* __restrict__ lv_b,
    float* __restrict__ out)
{
    __shared__ float hl[HID];
    const int b = blockIdx.x, tid = threadIdx.x;
    for (int k = tid; k < HID; k += 128) hl[k] = h[b * HID + k];
    __syncthreads();

    const float* W = (tid < 64) ? lin_w : lv_w;
    const int j = tid & 63;
    const float4* W4 = (const float4*)(W + j * HID);
    float acc = 0.0f;
    for (int k4 = 0; k4 < HID / 4; ++k4) {
        float4 wv = W4[k4];
        float4 hv = *(const float4*)(hl + k4 * 4);
        acc += wv.x * hv.x + wv.y * hv.y + wv.z * hv.z + wv.w * hv.w;
    }

    if (tid < 64) {
        out[b * OUTD + j] = __expf(acc + lin_b[j]) * 0.1f;
    } else {
        out[BATCH * OUTD + b * OUTD + j] = acc + lv_b[j] - 5.0f;
    }
}

// ---------------------------------------------------------------------------
extern "C" void kernel_launch(void* const* d_in, const int* in_sizes, int n_in,
                              void* d_out, int out_size, void* d_ws, size_t ws_size,
                              hipStream_t stream)
{
    const float* x     = (const float*)d_in[0];
    const float* a     = (const float*)d_in[1];
    const float* mask  = (const float*)d_in[2];
    const float* W_ih  = (const float*)d_in[3];
    const float* W_hh  = (const float*)d_in[4];
    const float* b_ih  = (const float*)d_in[5];
    const float* b_hh  = (const float*)d_in[6];
    const float* lin_w = (const float*)d_in[7];
    const float* lin_b = (const float*)d_in[8];
    const float* lv_w  = (const float*)d_in[9];
    const float* lv_b  = (const float*)d_in[10];

    uint8_t* ws = (uint8_t*)d_ws;

    precompute_kernel<<<512, 256, 0, stream>>>(x, a, mask, ws);
    lstm_persist_kernel<<<NBT * NUT, 512, 0, stream>>>(W_ih, W_hh, b_ih, b_hh, ws);
    head_kernel<<<BATCH, 128, 0, stream>>>((const float*)(ws + HF_OFF),
                                           lin_w, lin_b, lv_w, lv_b, (float*)d_out);
}